// Round 1
// baseline (48.141 us; speedup 1.0000x reference)
//
#include <hip/hip_runtime.h>
#include <math.h>

// Problem constants (from reference): x is (B=256, N=1024, D=256) fp32.
// Output = softmax(x[b,0,:] @ x[b]^T / 16) @ x[b]  -> (256, 1, 256) fp32.
constexpr int BATCH = 256;
constexpr int N = 1024;
constexpr int D = 256;
constexpr int WAVES = 16;          // 1024 threads / 64
constexpr int THREADS = WAVES * 64;
constexpr int KEYS_PER_WAVE = N / WAVES;   // 64
constexpr int CHUNK = 4;
constexpr int NCHUNK = KEYS_PER_WAVE / CHUNK; // 16

__global__ __launch_bounds__(THREADS, 1)
void attn_q0_kernel(const float* __restrict__ x, float* __restrict__ out) {
    const int b    = blockIdx.x;
    const int tid  = threadIdx.x;
    const int wave = tid >> 6;
    const int lane = tid & 63;

    const float* __restrict__ xb = x + (size_t)b * (N * D);

    // q fragment: lane i holds q[4i..4i+3]  (row 0 of this batch; L1/L2 hit across waves)
    const float4 q4 = *reinterpret_cast<const float4*>(xb + lane * 4);

    // this wave's key rows: fully coalesced 1 KiB per row per wave
    const float* __restrict__ base = xb + (size_t)(wave * KEYS_PER_WAVE) * D + lane * 4;

    float  m_run = -INFINITY;
    float  l_run = 0.f;
    float4 o4    = make_float4(0.f, 0.f, 0.f, 0.f);

    float4 v[CHUNK];
#pragma unroll
    for (int j = 0; j < CHUNK; ++j)
        v[j] = *reinterpret_cast<const float4*>(base + j * D);

    for (int c = 0; c < NCHUNK; ++c) {
        // prefetch next chunk (keeps 4 loads/wave in flight across the compute)
        float4 vn[CHUNK];
        const bool more = (c + 1 < NCHUNK);
        if (more) {
#pragma unroll
            for (int j = 0; j < CHUNK; ++j)
                vn[j] = *reinterpret_cast<const float4*>(base + ((c + 1) * CHUNK + j) * D);
        }

        // scores for the 4 keys (independent butterfly reduces -> ILP)
        float s[CHUNK];
#pragma unroll
        for (int j = 0; j < CHUNK; ++j) {
            float p = q4.x * v[j].x + q4.y * v[j].y + q4.z * v[j].z + q4.w * v[j].w;
#pragma unroll
            for (int off = 32; off >= 1; off >>= 1)
                p += __shfl_xor(p, off, 64);
            s[j] = p * 0.0625f;   // 1/sqrt(256)
        }

        // online softmax update, one rescale per 4 keys
        float mnew = m_run;
#pragma unroll
        for (int j = 0; j < CHUNK; ++j) mnew = fmaxf(mnew, s[j]);
        const float alpha = __expf(m_run - mnew);  // first chunk: exp(-inf)=0, zeroes o4/l_run
        float pj[CHUNK];
        float psum = 0.f;
#pragma unroll
        for (int j = 0; j < CHUNK; ++j) { pj[j] = __expf(s[j] - mnew); psum += pj[j]; }
        l_run = l_run * alpha + psum;
        o4.x *= alpha; o4.y *= alpha; o4.z *= alpha; o4.w *= alpha;
#pragma unroll
        for (int j = 0; j < CHUNK; ++j) {
            o4.x += pj[j] * v[j].x;
            o4.y += pj[j] * v[j].y;
            o4.z += pj[j] * v[j].z;
            o4.w += pj[j] * v[j].w;
        }
        m_run = mnew;

        if (more) {
#pragma unroll
            for (int j = 0; j < CHUNK; ++j) v[j] = vn[j];
        }
    }

    // combine 16 per-wave partials through LDS
    __shared__ float s_o[WAVES][D];
    __shared__ float s_m[WAVES];
    __shared__ float s_l[WAVES];

    *reinterpret_cast<float4*>(&s_o[wave][lane * 4]) = o4;
    if (lane == 0) { s_m[wave] = m_run; s_l[wave] = l_run; }
    __syncthreads();

    if (tid < D) {
        float M = -INFINITY;
#pragma unroll
        for (int w = 0; w < WAVES; ++w) M = fmaxf(M, s_m[w]);
        float L = 0.f, acc = 0.f;
#pragma unroll
        for (int w = 0; w < WAVES; ++w) {
            const float e = __expf(s_m[w] - M);
            L   += s_l[w] * e;
            acc += s_o[w][tid] * e;
        }
        out[(size_t)b * D + tid] = acc / L;
    }
}

extern "C" void kernel_launch(void* const* d_in, const int* in_sizes, int n_in,
                              void* d_out, int out_size, void* d_ws, size_t ws_size,
                              hipStream_t stream) {
    const float* x = (const float*)d_in[0];
    float* out = (float*)d_out;
    attn_q0_kernel<<<BATCH, THREADS, 0, stream>>>(x, out);
}